// Round 1
// baseline (489.665 us; speedup 1.0000x reference)
//
#include <hip/hip_runtime.h>

// DilateAttention: B=16, C=384, H=W=56, heads of 32, ksq=9 (3x3, dilation 2,
// reflect pad 2). Memory-bound: ~308 MB ideal HBM traffic -> ~49 us floor.
//
// One thread per (b, head, h, w). w is the fastest-varying thread index so
// q/k/v scalar loads are lane-contiguous. Output is channels-last; each
// thread owns out[b,h,w, n*32 .. n*32+31] = 128 contiguous bytes, stored as
// 8 x float4 (each cache line fully written by one thread).

#define BB 16
#define CH 384
#define HH 56
#define WW 56
#define NH 12
#define DD 32
#define HW (HH * WW)
#define KSQ 9
#define SCALE 0.17677669529663687f  // 32^-0.5

__global__ __launch_bounds__(256, 4)
void dilate_attn_kernel(const float* __restrict__ q,
                        const float* __restrict__ k,
                        const float* __restrict__ v,
                        float* __restrict__ out) {
    int t = blockIdx.x * 256 + threadIdx.x;
    int w = t % WW;
    int h = (t / WW) % HH;
    int n = (t / HW) % NH;
    int b = t / (HW * NH);

    // Reflected dilated-neighbor offsets within one [H,W] plane.
    int off[KSQ];
#pragma unroll
    for (int i = 0; i < 3; ++i) {
        int r = h + 2 * (i - 1);
        r = (r < 0) ? -r : ((r >= HH) ? (2 * HH - 2 - r) : r);
#pragma unroll
        for (int j = 0; j < 3; ++j) {
            int c = w + 2 * (j - 1);
            c = (c < 0) ? -c : ((c >= WW) ? (2 * WW - 2 - c) : c);
            off[i * 3 + j] = r * WW + c;
        }
    }

    const long base = (long)(b * CH + n * DD) * HW;
    const float* qp = q + base + h * WW + w;
    const float* kp = k + base;
    const float* vp = v + base;

    // ---- pass 1: scores s[j] = sum_d q[d] * k[d, off[j]] ----
    float s[KSQ];
#pragma unroll
    for (int j = 0; j < KSQ; ++j) s[j] = 0.f;

#pragma unroll 4
    for (int d = 0; d < DD; ++d) {
        float qd = qp[d * HW];
        const float* kd = kp + d * HW;
#pragma unroll
        for (int j = 0; j < KSQ; ++j) {
            s[j] = fmaf(qd, kd[off[j]], s[j]);
        }
    }

    // ---- softmax over the 9 scores (scale folded into the exp) ----
    float m = s[0];
#pragma unroll
    for (int j = 1; j < KSQ; ++j) m = fmaxf(m, s[j]);
    float a[KSQ];
    float sum = 0.f;
#pragma unroll
    for (int j = 0; j < KSQ; ++j) {
        a[j] = __expf((s[j] - m) * SCALE);
        sum += a[j];
    }
    float inv = 1.f / sum;
#pragma unroll
    for (int j = 0; j < KSQ; ++j) a[j] *= inv;

    // ---- pass 2: out[d] = sum_j a[j] * v[d, off[j]]; store channels-last ----
    float* op = out + ((long)(b * HH + h) * WW + w) * CH + n * DD;
#pragma unroll 2
    for (int d4 = 0; d4 < DD / 4; ++d4) {
        float ob[4];
#pragma unroll
        for (int e = 0; e < 4; ++e) {
            int d = d4 * 4 + e;
            const float* vd = vp + d * HW;
            float acc = 0.f;
#pragma unroll
            for (int j = 0; j < KSQ; ++j) {
                acc = fmaf(a[j], vd[off[j]], acc);
            }
            ob[e] = acc;
        }
        // 16B-aligned: base offset is a multiple of 32 floats.
        *(float4*)(op + d4 * 4) = make_float4(ob[0], ob[1], ob[2], ob[3]);
    }
}

extern "C" void kernel_launch(void* const* d_in, const int* in_sizes, int n_in,
                              void* d_out, int out_size, void* d_ws, size_t ws_size,
                              hipStream_t stream) {
    const float* q = (const float*)d_in[0];
    const float* k = (const float*)d_in[1];
    const float* v = (const float*)d_in[2];
    float* out = (float*)d_out;

    const int total = BB * NH * HH * WW;  // 602112 threads, one per pixel-head
    dilate_attn_kernel<<<total / 256, 256, 0, stream>>>(q, k, v, out);
}

// Round 2
// 395.116 us; speedup vs baseline: 1.2393x; 1.2393x over previous
//
#include <hip/hip_runtime.h>

// DilateAttention: B=16, C=384 (12 heads x 32), H=W=56, 3x3 window, dil=2,
// reflect pad. Memory-bound; ideal HBM ~308 MB -> ~49 us floor.
//
// R2: w-strip register blocking. One thread = 4 consecutive pixels (aligned
// w-strip). Per (channel,row) the 3 column-offsets (dc=-2,0,+2) for 4 pixels
// are served by 3 aligned float4 loads A=[w4-4..w4-1] B=[w4..w4+3]
// C=[w4+4..w4+7]; reflection at the w edges is handled with component
// selects on clamped (always-valid, aligned) loads - no divergent loads.
// Cuts VMEM instruction count 4x vs the scalar round-1 kernel.

#define BB 16
#define CH 384
#define HH 56
#define WW 56
#define NH 12
#define DD 32
#define HW (HH * WW)
#define KSQ 9
#define SW 14                      // strips per row (56/4)
#define SCALE 0.17677669529663687f // 32^-0.5

__global__ __launch_bounds__(256, 2)
void dilate_attn_kernel(const float* __restrict__ q,
                        const float* __restrict__ k,
                        const float* __restrict__ v,
                        float* __restrict__ out) {
    int t = blockIdx.x * 256 + threadIdx.x;
    int ws = (t % SW) * 4;             // strip start col (0,4,...,52)
    int h  = (t / SW) % HH;
    int n  = (t / (SW * HH)) % NH;
    int b  = t / (SW * HH * NH);

    const bool isL = (ws == 0);
    const bool isR = (ws == 52);
    const int aoff = isL ? 0  : ws - 4;   // clamped, 16B-aligned, always valid
    const int coff = isR ? 48 : ws + 4;

    // reflected row offsets (floats) for dr = -2, 0, +2
    int roff[3];
#pragma unroll
    for (int i = 0; i < 3; ++i) {
        int r = h + 2 * (i - 1);
        r = (r < 0) ? -r : ((r >= HH) ? (2 * HH - 2 - r) : r);
        roff[i] = r * WW;
    }

    const int base = (b * CH + n * DD) * HW;
    const float* qrow = q + base + h * WW + ws;
    const float* kp = k + base;
    const float* vp = v + base;

    // ---- pass 1: scores s[p][i*3+j] for 4 pixels x 9 offsets ----
    float s[4][KSQ];
#pragma unroll
    for (int p = 0; p < 4; ++p)
#pragma unroll
        for (int j = 0; j < KSQ; ++j) s[p][j] = 0.f;

#pragma unroll 4
    for (int d = 0; d < DD; ++d) {
        const float4 Q = *(const float4*)(qrow + d * HW);
        const float* kd = kp + d * HW;
#pragma unroll
        for (int i = 0; i < 3; ++i) {
            const float* rr = kd + roff[i];
            float4 A = *(const float4*)(rr + aoff);
            float4 B = *(const float4*)(rr + ws);
            float4 C = *(const float4*)(rr + coff);
            // cols w-2,w-1 for pixels 0,1 (reflect at left edge -> cols 2,1)
            float l0 = isL ? B.z : A.z;
            float l1 = isL ? B.y : A.w;
            // cols w+4,w+5 for pixels 2,3 (reflect at right edge -> 54,53)
            float r2 = isR ? B.z : C.x;
            float r3 = isR ? B.y : C.y;
            // j=0 (dc=-2): pixel p reads col ws+p-2
            s[0][i*3+0] = fmaf(Q.x, l0,  s[0][i*3+0]);
            s[1][i*3+0] = fmaf(Q.y, l1,  s[1][i*3+0]);
            s[2][i*3+0] = fmaf(Q.z, B.x, s[2][i*3+0]);
            s[3][i*3+0] = fmaf(Q.w, B.y, s[3][i*3+0]);
            // j=1 (dc=0)
            s[0][i*3+1] = fmaf(Q.x, B.x, s[0][i*3+1]);
            s[1][i*3+1] = fmaf(Q.y, B.y, s[1][i*3+1]);
            s[2][i*3+1] = fmaf(Q.z, B.z, s[2][i*3+1]);
            s[3][i*3+1] = fmaf(Q.w, B.w, s[3][i*3+1]);
            // j=2 (dc=+2)
            s[0][i*3+2] = fmaf(Q.x, B.z, s[0][i*3+2]);
            s[1][i*3+2] = fmaf(Q.y, B.w, s[1][i*3+2]);
            s[2][i*3+2] = fmaf(Q.z, r2,  s[2][i*3+2]);
            s[3][i*3+2] = fmaf(Q.w, r3,  s[3][i*3+2]);
        }
    }

    // ---- softmax over 9 (scale folded into exp), in place ----
#pragma unroll
    for (int p = 0; p < 4; ++p) {
        float m = s[p][0];
#pragma unroll
        for (int j = 1; j < KSQ; ++j) m = fmaxf(m, s[p][j]);
        float sum = 0.f;
#pragma unroll
        for (int j = 0; j < KSQ; ++j) {
            s[p][j] = __expf((s[p][j] - m) * SCALE);
            sum += s[p][j];
        }
        float inv = 1.f / sum;
#pragma unroll
        for (int j = 0; j < KSQ; ++j) s[p][j] *= inv;
    }

    // ---- pass 2: out[p][d] = sum_j a[p][j] * v[...]; store channels-last ----
    float* op = out + ((b * HH + h) * WW + ws) * CH + n * DD;
#pragma unroll 2
    for (int d4 = 0; d4 < DD / 4; ++d4) {
        float o[4][4];
#pragma unroll
        for (int p = 0; p < 4; ++p)
#pragma unroll
            for (int e = 0; e < 4; ++e) o[p][e] = 0.f;
#pragma unroll
        for (int e = 0; e < 4; ++e) {
            const float* vd = vp + (d4 * 4 + e) * HW;
#pragma unroll
            for (int i = 0; i < 3; ++i) {
                const float* rr = vd + roff[i];
                float4 A = *(const float4*)(rr + aoff);
                float4 B = *(const float4*)(rr + ws);
                float4 C = *(const float4*)(rr + coff);
                float l0 = isL ? B.z : A.z;
                float l1 = isL ? B.y : A.w;
                float r2 = isR ? B.z : C.x;
                float r3 = isR ? B.y : C.y;
                o[0][e] = fmaf(s[0][i*3+0], l0,  fmaf(s[0][i*3+1], B.x, fmaf(s[0][i*3+2], B.z, o[0][e])));
                o[1][e] = fmaf(s[1][i*3+0], l1,  fmaf(s[1][i*3+1], B.y, fmaf(s[1][i*3+2], B.w, o[1][e])));
                o[2][e] = fmaf(s[2][i*3+0], B.x, fmaf(s[2][i*3+1], B.z, fmaf(s[2][i*3+2], r2,  o[2][e])));
                o[3][e] = fmaf(s[3][i*3+0], B.y, fmaf(s[3][i*3+1], B.w, fmaf(s[3][i*3+2], r3,  o[3][e])));
            }
        }
#pragma unroll
        for (int p = 0; p < 4; ++p) {
            *(float4*)(op + p * CH + d4 * 4) =
                make_float4(o[p][0], o[p][1], o[p][2], o[p][3]);
        }
    }
}

extern "C" void kernel_launch(void* const* d_in, const int* in_sizes, int n_in,
                              void* d_out, int out_size, void* d_ws, size_t ws_size,
                              hipStream_t stream) {
    const float* q = (const float*)d_in[0];
    const float* k = (const float*)d_in[1];
    const float* v = (const float*)d_in[2];
    float* out = (float*)d_out;

    const int total = BB * NH * HH * SW;  // 150528 threads, one per 4-pixel strip
    dilate_attn_kernel<<<total / 256, 256, 0, stream>>>(q, k, v, out);
}

// Round 3
// 279.488 us; speedup vs baseline: 1.7520x; 1.4137x over previous
//
#include <hip/hip_runtime.h>
#include <stdint.h>

// DilateAttention: B=16, C=384 (12 heads x 32), H=W=56, 3x3 window, dil=2,
// reflect pad. Memory-bound; ideal HBM ~308 MB.
//
// R3: latency -> streaming restructure. R1/R2 post-mortem showed the VMEM
// gather path plateaus at ~10 B/cyc/CU (latency-bound, occupancy 20%).
// New shape: block = (b, head, 8-row band). k/v tiles stream into LDS with
// async global_load_lds (width 16, double-buffered, d-chunks of 8); the
// 9-point dilated window is then read from LDS at short latency. Scores and
// attention weights live in registers across chunks.
//   blocks = 16*12*7 = 1344 (5.25/CU), 448 thr/block, LDS 43008 B -> 3 blk/CU.

#define BB 16
#define CH 384
#define HH 56
#define WW 56
#define NH 12
#define DD 32
#define HW (HH * WW)
#define KSQ 9
#define SCALE 0.17677669529663687f  // 32^-0.5

#define BAND 8                 // pixel rows per block
#define DCH 8                  // d-channels per staged chunk
#define NCHUNK (DD / DCH)      // 4
#define MAXROWS 12             // band + 2*halo
#define SLICE (MAXROWS * WW)   // floats per d-slice in LDS (672)
#define LBUF (DCH * SLICE)     // floats per buffer (5376)

__device__ __forceinline__ void async16(const void* g, void* l) {
    __builtin_amdgcn_global_load_lds(
        (const __attribute__((address_space(1))) void*)g,
        (__attribute__((address_space(3))) void*)l, 16, 0, 0);
}

// Stage one d-chunk (DCH planes x nr rows x 56 cols) into ldsbuf.
// plane0 points at row `lo` of the first d-plane of the chunk. Sbytes = nr*224.
// Each d-slice is covered by three 1KB wave-instrs: offsets 0, 1024, S-1024
// (the third overlaps the second; duplicate writes carry identical data).
__device__ __forceinline__ void stage_chunk(const float* __restrict__ plane0,
                                            float* ldsbuf, int Sbytes,
                                            int wv, int lane) {
    const int lo16 = lane * 16;
    for (int s = wv; s < DCH; s += 7) {      // 7 waves cover 8 slices
        const char* g = (const char*)(plane0 + s * HW);
        char* l = (char*)(ldsbuf + s * SLICE);
        async16(g + lo16, l + lo16);
        async16(g + 1024 + lo16, l + 1024 + lo16);
        const int t = Sbytes - 1024;
        async16(g + t + lo16, l + t + lo16);
    }
}

__global__ __launch_bounds__(448, 5)
void dilate_attn_kernel(const float* __restrict__ q,
                        const float* __restrict__ k,
                        const float* __restrict__ v,
                        float* __restrict__ out) {
    __shared__ float lds[2][LBUF];  // 43008 B

    const int band = blockIdx.x;       // 0..6
    const int n    = blockIdx.y;       // head
    const int b    = blockIdx.z;

    const int tid  = threadIdx.x;      // 0..447
    const int lane = tid & 63;
    const int wv   = tid >> 6;

    const int w = tid % WW;
    const int r = tid / WW;            // 0..7
    const int h0 = band * BAND;
    const int h  = h0 + r;

    // staged (clamped, contiguous) row range
    const int lo = (h0 - 2 < 0) ? 0 : h0 - 2;
    const int hi = (h0 + 9 > HH - 1) ? HH - 1 : h0 + 9;
    const int Sbytes = (hi - lo + 1) * WW * 4;   // 2240 or 2688

    // 9 window offsets inside an LDS d-slice (reflected rows/cols)
    int off9[KSQ];
    {
        int wc[3];
#pragma unroll
        for (int j = 0; j < 3; ++j) {
            int c = w + 2 * (j - 1);
            c = (c < 0) ? -c : ((c >= WW) ? (2 * WW - 2 - c) : c);
            wc[j] = c;
        }
#pragma unroll
        for (int i = 0; i < 3; ++i) {
            int rr = h + 2 * (i - 1);
            rr = (rr < 0) ? -rr : ((rr >= HH) ? (2 * HH - 2 - rr) : rr);
            rr -= lo;                  // LDS row index, in [0, nr)
#pragma unroll
            for (int j = 0; j < 3; ++j) off9[i * 3 + j] = rr * WW + wc[j];
        }
    }

    const int planebase = (b * CH + n * DD) * HW;     // first d-plane of head
    const float* qp = q + planebase + h * WW + w;
    const float* kstage = k + planebase + lo * WW;
    const float* vstage = v + planebase + lo * WW;

    float sc[KSQ];
#pragma unroll
    for (int ii = 0; ii < KSQ; ++ii) sc[ii] = 0.f;

    // ---------------- pass 1: scores over 4 k-chunks ----------------
    stage_chunk(kstage, lds[0], Sbytes, wv, lane);
    __syncthreads();
    int cur = 0;

    for (int c = 0; c < NCHUNK; ++c) {
        if (c < NCHUNK - 1)
            stage_chunk(kstage + (c + 1) * DCH * HW, lds[cur ^ 1], Sbytes, wv, lane);
        else
            stage_chunk(vstage, lds[cur ^ 1], Sbytes, wv, lane);

        float qd[DCH];
#pragma unroll
        for (int j = 0; j < DCH; ++j) qd[j] = qp[(c * DCH + j) * HW];

        const float* Bf = lds[cur];
#pragma unroll
        for (int j = 0; j < DCH; ++j) {
            const float* Ls = Bf + j * SLICE;
            const float qj = qd[j];
#pragma unroll
            for (int ii = 0; ii < KSQ; ++ii)
                sc[ii] = fmaf(qj, Ls[off9[ii]], sc[ii]);
        }
        __syncthreads();
        cur ^= 1;
    }

    // ---------------- softmax over the 9 positions ----------------
    {
        float m = sc[0];
#pragma unroll
        for (int ii = 1; ii < KSQ; ++ii) m = fmaxf(m, sc[ii]);
        float sum = 0.f;
#pragma unroll
        for (int ii = 0; ii < KSQ; ++ii) {
            sc[ii] = __expf((sc[ii] - m) * SCALE);
            sum += sc[ii];
        }
        const float inv = 1.f / sum;
#pragma unroll
        for (int ii = 0; ii < KSQ; ++ii) sc[ii] *= inv;
    }

    // ---------------- pass 2: output over 4 v-chunks ----------------
    float* op = out + ((b * HH + h) * WW + w) * CH + n * DD;

    for (int c = 0; c < NCHUNK; ++c) {
        if (c < NCHUNK - 1)
            stage_chunk(vstage + (c + 1) * DCH * HW, lds[cur ^ 1], Sbytes, wv, lane);

        const float* Bf = lds[cur];
        float o[DCH];
#pragma unroll
        for (int j = 0; j < DCH; ++j) {
            const float* Ls = Bf + j * SLICE;
            float acc = 0.f;
#pragma unroll
            for (int ii = 0; ii < KSQ; ++ii)
                acc = fmaf(sc[ii], Ls[off9[ii]], acc);
            o[j] = acc;
        }
        *(float4*)(op + c * DCH)     = make_float4(o[0], o[1], o[2], o[3]);
        *(float4*)(op + c * DCH + 4) = make_float4(o[4], o[5], o[6], o[7]);

        if (c < NCHUNK - 1) {
            __syncthreads();
            cur ^= 1;
        }
    }
}

extern "C" void kernel_launch(void* const* d_in, const int* in_sizes, int n_in,
                              void* d_out, int out_size, void* d_ws, size_t ws_size,
                              hipStream_t stream) {
    const float* q = (const float*)d_in[0];
    const float* k = (const float*)d_in[1];
    const float* v = (const float*)d_in[2];
    float* out = (float*)d_out;

    dim3 grid(HH / BAND, NH, BB);   // 7 x 12 x 16 = 1344 blocks
    dilate_attn_kernel<<<grid, 448, 0, stream>>>(q, k, v, out);
}